// Round 1
// baseline (143.617 us; speedup 1.0000x reference)
//
#include <hip/hip_runtime.h>
#include <math.h>

#define LN2F 0.69314718055994530942f

// ws layout (floats)
#define WS_PWMLOG 0      // 240 : log-softmax of pwm_logits (3,20,4)
#define WS_PJT    240    // 6   : p_{j,t}
#define WS_WPROD  246    // 8   : prod_j p_{j,bit_j(iw)}
#define WS_BASEP  254    // scalar: dir_lp(pwm).sum + binom part of log_prior
#define WS_BASEG  255    // scalar: base log_guide
#define WS_WVF    256    // 6   : w value (float) per (j,t)
#define WS_Y      272    // 6*50*100 = 30000 : y planes [jt][b][q]
#define WS_GAMMA  30272  // 8*50*3 = 1200
#define WS_ZT     31472  // 3*300 : prior/guide/lpv terms per (It,b)

__device__ __forceinline__ float sigm(float x){ return 1.0f/(1.0f+expf(-x)); }
__device__ __forceinline__ float mishf(float x){
    float sp = fmaxf(x,0.0f) + log1pf(expf(-fabsf(x)));
    return x * tanhf(sp);
}

// ---------------- Kernel A : prelude (1 block, 64 threads) ----------------
__global__ void kA(const float* __restrict__ pwm_logits,
                   const float* __restrict__ wn_W1, const float* __restrict__ wn_b1,
                   const float* __restrict__ wn_W2, const float* __restrict__ wn_b2,
                   const float* __restrict__ wn_W3, const float* __restrict__ wn_b3,
                   float* __restrict__ ws)
{
    __shared__ float red[64];
    __shared__ float h1[16], h2s[16];
    int tid = threadIdx.x;
    float C4 = lgammaf(0.8f) - 4.0f*lgammaf(0.2f);
    float part = 0.0f;
    if (tid < 60) {   // 3*20 rows of softmax over 4
        const float* l = pwm_logits + tid*4;
        float m = fmaxf(fmaxf(l[0],l[1]),fmaxf(l[2],l[3]));
        float se = expf(l[0]-m)+expf(l[1]-m)+expf(l[2]-m)+expf(l[3]-m);
        float ls = logf(se);
        float dsum = 0.0f;
        for(int c=0;c<4;c++){ float pl = l[c]-m-ls; ws[WS_PWMLOG+tid*4+c]=pl; dsum+=pl; }
        float lp = -0.8f*dsum + C4;          // (alpha-1)=-0.8
        part = fminf(3.0f, lp);
    }
    red[tid]=part;
    __syncthreads();
    for(int s=32;s>0;s>>=1){ if(tid<s) red[tid]+=red[tid+s]; __syncthreads(); }

    if (tid<16) h1[tid] = mishf(wn_W1[tid]+wn_b1[tid]);
    __syncthreads();
    if (tid<16){
        float acc = wn_b2[tid];
        for(int i=0;i<16;i++) acc += h1[i]*wn_W2[i*16+tid];
        h2s[tid]=mishf(acc);
    }
    __syncthreads();
    if (tid==0){
        float mean[3];
        for(int o=0;o<3;o++){
            float acc=wn_b3[o];
            for(int i=0;i<16;i++) acc += h2s[i]*wn_W3[i*3+o];
            mean[o] = sigm(acc)*15.0f + 5.0f;    // ww*(W1-W0)+W0
        }
        float pjt[3][2], wlp[3][2], bin[3][2];
        for(int j=0;j<3;j++){
            for(int t=0;t<2;t++){
                float wv = t ? ceilf(mean[j]) : floorf(mean[j]);
                float up = (wv>=20.0f)?1.0f:sigm((wv+0.5f-mean[j])/0.05f);
                float lo = (wv<=5.0f)?0.0f:sigm((wv-0.5f-mean[j])/0.05f);
                wlp[j][t] = logf(up-lo+1e-12f);
                pjt[j][t] = expf(wlp[j][t]);
                bin[j][t] = lgammaf(16.0f)-lgammaf(wv+1.0f)-lgammaf(16.0f-wv)+15.0f*(-LN2F);
                ws[WS_PJT+j*2+t]=pjt[j][t];
                ws[WS_WVF+j*2+t]=wv;
            }
        }
        float bp = red[0];
        float bg = 0.0f;
        for(int i=0;i<8;i++){
            int b0=(i>>2)&1, b1=(i>>1)&1, b2=i&1;
            float wp = pjt[0][b0]*pjt[1][b1]*pjt[2][b2];
            ws[WS_WPROD+i]=wp;
            bp += wp*(bin[0][b0]+bin[1][b1]+bin[2][b2]);
            bg += wp*(wlp[0][b0]+wlp[1][b1]+wlp[2][b2]);
        }
        ws[WS_BASEP]=bp;
        ws[WS_BASEG]=bg;
    }
}

// ---------------- Kernel B : y planes, grid (6,50), 128 threads ----------------
__global__ void kB(const int* __restrict__ X, float* __restrict__ ws)
{
    int jt = blockIdx.x, b = blockIdx.y;
    int j = jt>>1;
    __shared__ int   xs[100];
    __shared__ float plj[80];
    int tid=threadIdx.x;
    if (tid<100) xs[tid]=X[b*100+tid];
    if (tid<80)  plj[tid]=ws[WS_PWMLOG+j*80+tid];
    __syncthreads();
    if (tid<100){
        int w = (int)ws[WS_WVF+jt];
        int left=(w-1)>>1;
        float yv=0.0f;
        if (tid>=left && tid<=left+100-w){
            int src=tid-left;
            float s=0.0f;
            for(int k=0;k<w;k++){
                int p=src+k; if(p>99)p=99;
                s+=plj[k*4+xs[p]];
            }
            yv=s/(float)w;
        }
        ws[WS_Y+(jt*50+b)*100+tid]=yv;
    }
}

// ---------------- Kernel C : gn branch -> gamma, grid (8,50), 256 threads ----------------
__global__ void kC(const float* __restrict__ c1W, const float* __restrict__ c1b,
                   const float* __restrict__ c2W, const float* __restrict__ c2b,
                   const float* __restrict__ l1W, const float* __restrict__ l1b,
                   const float* __restrict__ l2W, const float* __restrict__ l2b,
                   float* __restrict__ ws)
{
    int iw=blockIdx.x, b=blockIdx.y, tid=threadIdx.x;
    __shared__ float yc[3][100];
    __shared__ float cw1[240];
    __shared__ float hp[16][48];
    __shared__ float c2o[44];
    __shared__ float g22[22];
    __shared__ float h16[16];
    for(int i=tid;i<300;i+=256){
        int j=i/100, q=i%100;
        int t=(iw>>(2-j))&1;
        yc[j][q]=ws[WS_Y+((j*2+t)*50+b)*100+q];
    }
    for(int i=tid;i<240;i+=256) cw1[i]=c1W[i];
    __syncthreads();
    for(int idx=tid; idx<768; idx+=256){            // conv1 + mish + pool
        int o=idx/48, p2=idx%48;
        float m=-1e30f;
        const float* wr=&cw1[o*15];
        for(int d=0;d<2;d++){
            int p=2*p2+d;
            float acc=c1b[o];
            for(int i=0;i<3;i++)
                for(int k=0;k<5;k++) acc += yc[i][p+k]*wr[i*5+k];
            m=fmaxf(m, mishf(acc));
        }
        hp[o][p2]=m;
    }
    __syncthreads();
    if (tid<44){                                    // conv2 + mish
        float acc=c2b[0];
        for(int i=0;i<16;i++)
            for(int k=0;k<5;k++) acc+=hp[i][tid+k]*c2W[i*5+k];
        c2o[tid]=mishf(acc);
    }
    __syncthreads();
    if (tid<22) g22[tid]=fmaxf(c2o[2*tid],c2o[2*tid+1]);
    __syncthreads();
    if (tid<16){
        float acc=l1b[tid];
        for(int i=0;i<22;i++) acc+=g22[i]*l1W[i*16+tid];
        h16[tid]=mishf(acc);
    }
    __syncthreads();
    if (tid==0){
        float o3[3]; float m=-1e30f;
        for(int o=0;o<3;o++){
            float acc=l2b[o];
            for(int i=0;i<16;i++) acc+=h16[i]*l2W[i*3+o];
            o3[o]=acc; m=fmaxf(m,acc);
        }
        float se=0.0f; for(int o=0;o<3;o++){o3[o]=expf(o3[o]-m); se+=o3[o];}
        for(int o=0;o<3;o++) ws[WS_GAMMA+(iw*50+b)*3+o]=o3[o]/se;
    }
}

// ---------------- Kernel D : zn branch -> per-(I,t,b) terms, grid (6,50), 256 threads ----------------
__global__ void kD(const int* __restrict__ X,
                   const float* __restrict__ c1W, const float* __restrict__ c1b,
                   const float* __restrict__ c2W, const float* __restrict__ c2b,
                   const float* __restrict__ clsW, const float* __restrict__ clsb,
                   const float* __restrict__ delW, const float* __restrict__ delb,
                   float* __restrict__ ws)
{
    int It=blockIdx.x, b=blockIdx.y, tid=threadIdx.x;
    int I=It>>1;
    __shared__ float y1[100];
    __shared__ int   xs[100];
    __shared__ float plI[80];
    __shared__ float zw1[80];
    __shared__ float zw2[640];
    __shared__ float hp[16][48];
    __shared__ float c2o[8][44];
    __shared__ float z[176];
    __shared__ float cls[9], del[10];
    if (tid<100){ y1[tid]=ws[WS_Y+(It*50+b)*100+tid]; xs[tid]=X[b*100+tid]; }
    if (tid>=128 && tid<208) { plI[tid-128]=ws[WS_PWMLOG+I*80+(tid-128)]; zw1[tid-128]=c1W[tid-128]; }
    for(int i=tid;i<640;i+=256) zw2[i]=c2W[i];
    __syncthreads();
    for(int idx=tid; idx<768; idx+=256){            // conv1 + mish + pool
        int o=idx/48, p2=idx%48;
        float m=-1e30f;
        for(int d=0;d<2;d++){
            int p=2*p2+d;
            float acc=c1b[o];
            for(int k=0;k<5;k++) acc+=y1[p+k]*zw1[o*5+k];
            m=fmaxf(m, mishf(acc));
        }
        hp[o][p2]=m;
    }
    __syncthreads();
    for(int idx=tid; idx<352; idx+=256){            // conv2 + mish
        int o=idx/44, p=idx%44;
        float acc=c2b[o];
        for(int i=0;i<16;i++)
            for(int k=0;k<5;k++) acc+=hp[i][p+k]*zw2[(o*16+i)*5+k];
        c2o[o][p]=mishf(acc);
    }
    __syncthreads();
    if (tid<176){                                   // pool -> z (176,)
        int o=tid/22, q=tid%22;
        z[tid]=fmaxf(c2o[o][2*q],c2o[o][2*q+1]);
    }
    __syncthreads();
    if (tid<9){
        float acc=clsb[tid];
        for(int m2=0;m2<176;m2++) acc+=z[m2]*clsW[m2*9+tid];
        cls[tid]=acc;
    }
    if (tid>=64 && tid<74){
        int n=tid-64;
        float acc=delb[n];
        for(int m2=0;m2<176;m2++) acc+=z[m2]*delW[m2*10+n];
        del[n]=sigm(acc);
    }
    __syncthreads();
    if (tid==0){
        int ind=0; float best=cls[0];
        for(int n=1;n<9;n++) if(cls[n]>best){best=cls[n];ind=n;}
        ind+=1;
        float Zm=((float)ind+del[ind])*7.9f;        // gap=(99-20)/10
        int wI=(int)ws[WS_WVF+It];
        float r0=0.0f,r1=0.0f,r2=0.0f;
        for(int s=0;s<2;s++){
            float zf = s? ceilf(Zm):floorf(Zm);
            float up = (zf>=99.0f)?1.0f:sigm((zf+0.5f-Zm)/0.05f);
            float lo = (zf<=0.0f)?0.0f:sigm((zf-0.5f-Zm)/0.05f);
            float zlp = logf(up-lo+1e-12f);
            float zp  = expf(zlp);
            float bin = lgammaf(80.0f)-lgammaf(zf+1.0f)-lgammaf(80.0f-zf)+79.0f*(-LN2F);
            int zi=(int)zf;
            float lpv=0.0f;
            for(int k=0;k<wI;k++){
                int p=zi+k; if(p<0)p=0; if(p>99)p=99;
                lpv+=plI[k*4+xs[p]];
            }
            r0+=zp*bin; r1+=zp*zlp; r2+=zp*lpv;
        }
        ws[WS_ZT+      It*50+b]=r0;
        ws[WS_ZT+300 + It*50+b]=r1;
        ws[WS_ZT+600 + It*50+b]=r2;
    }
}

// ---------------- Kernel E : final contraction (1 block, 256 threads) ----------------
__global__ void kE(const float* __restrict__ ws, float* __restrict__ out)
{
    int tid=threadIdx.x;
    __shared__ float sa[256], sb[256], sc[256];
    float C3 = lgammaf(0.6f) - 3.0f*lgammaf(0.2f);
    float pp=0.0f, pg=0.0f, px=0.0f;
    for(int idx=tid; idx<400; idx+=256){            // gamma Dirichlet prior
        int iw=idx/50, b=idx%50;
        const float* g=&ws[WS_GAMMA+(iw*50+b)*3];
        float lp=-0.8f*(logf(g[0])+logf(g[1])+logf(g[2]))+C3;
        lp=fminf(3.0f,lp);
        pp += ws[WS_WPROD+iw]*lp;
    }
    for(int idx=tid; idx<300; idx+=256){            // z-branch contraction
        int It=idx/50, b=idx%50;
        int I=It>>1, t=It&1;
        float gs=0.0f;
        for(int iw=0;iw<8;iw++)
            if(((iw>>(2-I))&1)==t) gs+=ws[WS_GAMMA+(iw*50+b)*3+I];
        float G=ws[WS_PJT+It]*gs;
        pp += G*ws[WS_ZT+idx];
        pg += G*ws[WS_ZT+300+idx];
        px += G*ws[WS_ZT+600+idx];
    }
    sa[tid]=pp; sb[tid]=pg; sc[tid]=px;
    __syncthreads();
    for(int s=128;s>0;s>>=1){
        if(tid<s){sa[tid]+=sa[tid+s];sb[tid]+=sb[tid+s];sc[tid]+=sc[tid+s];}
        __syncthreads();
    }
    if(tid==0){
        float log_prior=ws[WS_BASEP]+sa[0];
        float log_guide=ws[WS_BASEG]+sb[0];
        float log_X=sc[0];
        out[0] = -log_X - log_prior + log_guide;
    }
}

extern "C" void kernel_launch(void* const* d_in, const int* in_sizes, int n_in,
                              void* d_out, int out_size, void* d_ws, size_t ws_size,
                              hipStream_t stream)
{
    const float* pwm_logits=(const float*)d_in[0];
    const float* wn_W1 =(const float*)d_in[1];
    const float* wn_b1 =(const float*)d_in[2];
    const float* wn_W2 =(const float*)d_in[3];
    const float* wn_b2 =(const float*)d_in[4];
    const float* wn_W3 =(const float*)d_in[5];
    const float* wn_b3 =(const float*)d_in[6];
    const float* gn_c1W=(const float*)d_in[7];
    const float* gn_c1b=(const float*)d_in[8];
    const float* gn_c2W=(const float*)d_in[9];
    const float* gn_c2b=(const float*)d_in[10];
    const float* gn_l1W=(const float*)d_in[11];
    const float* gn_l1b=(const float*)d_in[12];
    const float* gn_l2W=(const float*)d_in[13];
    const float* gn_l2b=(const float*)d_in[14];
    const float* zn_c1W=(const float*)d_in[15];
    const float* zn_c1b=(const float*)d_in[16];
    const float* zn_c2W=(const float*)d_in[17];
    const float* zn_c2b=(const float*)d_in[18];
    const float* zn_clsW=(const float*)d_in[19];
    const float* zn_clsb=(const float*)d_in[20];
    const float* zn_delW=(const float*)d_in[21];
    const float* zn_delb=(const float*)d_in[22];
    const int*   X     =(const int*)d_in[23];
    float* ws =(float*)d_ws;
    float* out=(float*)d_out;

    hipLaunchKernelGGL(kA, dim3(1),      dim3(64),  0, stream,
                       pwm_logits, wn_W1, wn_b1, wn_W2, wn_b2, wn_W3, wn_b3, ws);
    hipLaunchKernelGGL(kB, dim3(6,50),   dim3(128), 0, stream, X, ws);
    hipLaunchKernelGGL(kC, dim3(8,50),   dim3(256), 0, stream,
                       gn_c1W, gn_c1b, gn_c2W, gn_c2b, gn_l1W, gn_l1b, gn_l2W, gn_l2b, ws);
    hipLaunchKernelGGL(kD, dim3(6,50),   dim3(256), 0, stream,
                       X, zn_c1W, zn_c1b, zn_c2W, zn_c2b, zn_clsW, zn_clsb, zn_delW, zn_delb, ws);
    hipLaunchKernelGGL(kE, dim3(1),      dim3(256), 0, stream, ws, out);
}

// Round 2
// 124.297 us; speedup vs baseline: 1.1554x; 1.1554x over previous
//
#include <hip/hip_runtime.h>
#include <math.h>

#define LN2F 0.69314718055994530942f

// ws layout (floats)
#define WS_GAMMA 0      // 8*50*3 = 1200 : gamma[iw][b][3]
#define WS_ZT    1200   // 3*300       : r0/r1/r2 per (It*50+b)

__device__ __forceinline__ float sigm(float x){ return 1.0f/(1.0f+expf(-x)); }
// mish(x) = x*tanh(softplus(x)) = x*(u-1)/(u+1), u=(1+e^x)^2  (exact identity)
__device__ __forceinline__ float mishf(float x){
    if (x >= 30.0f) return x;            // tanh(softplus(30)) = 1 - 2e-26
    float w = expf(x);
    float u = 1.0f + w; u *= u;
    return x * (u - 1.0f) / (u + 1.0f);
}

// ---------- kMain : grid(700) x 256. bid<400: gamma task (iw,b). else: z task (It,b).
__global__ __launch_bounds__(256) void kMain(
    const float* __restrict__ pwm_logits,
    const float* __restrict__ wn_W1, const float* __restrict__ wn_b1,
    const float* __restrict__ wn_W2, const float* __restrict__ wn_b2,
    const float* __restrict__ wn_W3, const float* __restrict__ wn_b3,
    const float* __restrict__ gc1W, const float* __restrict__ gc1b,
    const float* __restrict__ gc2W, const float* __restrict__ gc2b,
    const float* __restrict__ gl1W, const float* __restrict__ gl1b,
    const float* __restrict__ gl2W, const float* __restrict__ gl2b,
    const float* __restrict__ zc1W, const float* __restrict__ zc1b,
    const float* __restrict__ zc2W, const float* __restrict__ zc2b,
    const float* __restrict__ zclsW, const float* __restrict__ zclsb,
    const float* __restrict__ zdelW, const float* __restrict__ zdelb,
    const int* __restrict__ X, float* __restrict__ ws)
{
    int tid=threadIdx.x, bid=blockIdx.x;
    bool isC = bid < 400;
    int iw=0, b, It=0, I=0;
    if(isC){ iw=bid%8; b=bid/8; }
    else   { int idx=bid-400; It=idx%6; b=idx/6; I=It>>1; }

    __shared__ float pl[240];          // log-softmax pwm (3,20,4)
    __shared__ int   xs[100];
    __shared__ float h1[16], h2[16], wv6[6];
    __shared__ float ybuf[3][100];
    __shared__ float w1buf[240];       // gn c1W (240) or zn c1W (80)
    __shared__ float zw2[640];
    __shared__ float hp[16][48];
    __shared__ float c2o[8][44];
    __shared__ float zz[176];
    __shared__ float cls[9], del[10];
    __shared__ float g22[22], h16[16];

    // ---- redundant prelude ----
    if(tid<60){
        const float* l=pwm_logits+tid*4;
        float m=fmaxf(fmaxf(l[0],l[1]),fmaxf(l[2],l[3]));
        float se=expf(l[0]-m)+expf(l[1]-m)+expf(l[2]-m)+expf(l[3]-m);
        float ls=logf(se);
        for(int c=0;c<4;c++) pl[tid*4+c]=l[c]-m-ls;
    }
    if(tid>=64 && tid<164) xs[tid-64]=X[b*100+tid-64];
    if(tid>=192 && tid<208) h1[tid-192]=mishf(wn_W1[tid-192]+wn_b1[tid-192]);
    __syncthreads();
    if(tid<16){
        float a=wn_b2[tid];
        for(int i=0;i<16;i++) a+=h1[i]*wn_W2[i*16+tid];
        h2[tid]=mishf(a);
    }
    __syncthreads();
    if(tid<6){
        int j=tid>>1;
        float a=wn_b3[j];
        for(int i=0;i<16;i++) a+=h2[i]*wn_W3[i*3+j];
        float mean=sigm(a)*15.0f+5.0f;
        wv6[tid]=(tid&1)?ceilf(mean):floorf(mean);
    }
    if(isC){ for(int i=tid;i<240;i+=256) w1buf[i]=gc1W[i]; }
    else{
        for(int i=tid;i<80;i+=256)  w1buf[i]=zc1W[i];
        for(int i=tid;i<640;i+=256) zw2[i]=zc2W[i];
    }
    __syncthreads();

    // ---- y plane(s) in-block ----
    int np = isC ? 3 : 1;
    for(int idx=tid; idx<np*100; idx+=256){
        int jj=idx/100, q=idx%100;
        int j = isC ? jj : I;
        int t = isC ? ((iw>>(2-jj))&1) : (It&1);
        int w=(int)wv6[j*2+t];
        int left=(w-1)>>1;
        float yv=0.0f;
        if(q>=left && q<=left+100-w){
            int src=q-left;
            float s=0.0f;
            const float* pj=&pl[j*80];
            for(int k=0;k<w;k++) s+=pj[k*4+xs[src+k]];
            yv=s/(float)w;
        }
        ybuf[jj][q]=yv;
    }
    __syncthreads();

    if(isC){
        // conv1(3->16,k5) + mish + maxpool2
        for(int idx=tid; idx<768; idx+=256){
            int o=idx/48, p2=idx%48;
            const float* wr=&w1buf[o*15];
            float bo=gc1b[o], m=-1e30f;
            for(int d=0;d<2;d++){
                int p=2*p2+d;
                float acc=bo;
                for(int i=0;i<3;i++)
                    for(int k=0;k<5;k++) acc+=ybuf[i][p+k]*wr[i*5+k];
                m=fmaxf(m,mishf(acc));
            }
            hp[o][p2]=m;
        }
        __syncthreads();
        if(tid<44){
            float acc=gc2b[0];
            for(int i=0;i<16;i++)
                for(int k=0;k<5;k++) acc+=hp[i][tid+k]*gc2W[i*5+k];
            c2o[0][tid]=mishf(acc);
        }
        __syncthreads();
        if(tid<22) g22[tid]=fmaxf(c2o[0][2*tid],c2o[0][2*tid+1]);
        __syncthreads();
        if(tid<16){
            float acc=gl1b[tid];
            for(int i=0;i<22;i++) acc+=g22[i]*gl1W[i*16+tid];
            h16[tid]=mishf(acc);
        }
        __syncthreads();
        if(tid==0){
            float o3[3], m=-1e30f;
            for(int o=0;o<3;o++){
                float acc=gl2b[o];
                for(int i=0;i<16;i++) acc+=h16[i]*gl2W[i*3+o];
                o3[o]=acc; m=fmaxf(m,acc);
            }
            float se=0.0f;
            for(int o=0;o<3;o++){ o3[o]=expf(o3[o]-m); se+=o3[o]; }
            float inv=1.0f/se;
            for(int o=0;o<3;o++) ws[WS_GAMMA+(iw*50+b)*3+o]=o3[o]*inv;
        }
    } else {
        for(int idx=tid; idx<768; idx+=256){
            int o=idx/48, p2=idx%48;
            const float* wr=&w1buf[o*5];
            float bo=zc1b[o], m=-1e30f;
            for(int d=0;d<2;d++){
                int p=2*p2+d;
                float acc=bo;
                for(int k=0;k<5;k++) acc+=ybuf[0][p+k]*wr[k];
                m=fmaxf(m,mishf(acc));
            }
            hp[o][p2]=m;
        }
        __syncthreads();
        for(int idx=tid; idx<352; idx+=256){
            int o=idx/44, p=idx%44;
            float acc=zc2b[o];
            for(int i=0;i<16;i++)
                for(int k=0;k<5;k++) acc+=hp[i][p+k]*zw2[(o*16+i)*5+k];
            c2o[o][p]=mishf(acc);
        }
        __syncthreads();
        if(tid<176){
            int o=tid/22, q=tid%22;
            zz[tid]=fmaxf(c2o[o][2*q],c2o[o][2*q+1]);
        }
        __syncthreads();
        if(tid<9){
            float acc=zclsb[tid];
            for(int m2=0;m2<176;m2++) acc+=zz[m2]*zclsW[m2*9+tid];
            cls[tid]=acc;
        }
        if(tid>=64 && tid<74){
            int n=tid-64;
            float acc=zdelb[n];
            for(int m2=0;m2<176;m2++) acc+=zz[m2]*zdelW[m2*10+n];
            del[n]=sigm(acc);
        }
        __syncthreads();
        if(tid==0){
            int ind=0; float best=cls[0];
            for(int n=1;n<9;n++) if(cls[n]>best){best=cls[n];ind=n;}
            ind+=1;
            float Zm=((float)ind+del[ind])*7.9f;   // gap=(99-20)/10
            int wI=(int)wv6[It];
            float r0=0,r1=0,r2=0;
            const float* pI=&pl[I*80];
            for(int s=0;s<2;s++){
                float zf=s?ceilf(Zm):floorf(Zm);
                float up=(zf>=99.0f)?1.0f:sigm((zf+0.5f-Zm)*20.0f);
                float lo=(zf<=0.0f)?0.0f:sigm((zf-0.5f-Zm)*20.0f);
                float zlp=logf(up-lo+1e-12f);
                float zp=expf(zlp);
                float bin=lgammaf(80.0f)-lgammaf(zf+1.0f)-lgammaf(80.0f-zf)-79.0f*LN2F;
                int zi=(int)zf;
                float lpv=0.0f;
                for(int k=0;k<wI;k++){
                    int p=zi+k; if(p>99)p=99;
                    lpv+=pI[k*4+xs[p]];
                }
                r0+=zp*bin; r1+=zp*zlp; r2+=zp*lpv;
            }
            ws[WS_ZT+    It*50+b]=r0;
            ws[WS_ZT+300+It*50+b]=r1;
            ws[WS_ZT+600+It*50+b]=r2;
        }
    }
}

// ---------- kFin : 1 block x 256 — scalar prelude + final contraction ----------
__global__ __launch_bounds__(256) void kFin(
    const float* __restrict__ pwm_logits,
    const float* __restrict__ wn_W1, const float* __restrict__ wn_b1,
    const float* __restrict__ wn_W2, const float* __restrict__ wn_b2,
    const float* __restrict__ wn_W3, const float* __restrict__ wn_b3,
    const float* __restrict__ ws, float* __restrict__ out)
{
    __shared__ float sa[256], sb[256], sc[256];
    __shared__ float h1[16], h2[16];
    __shared__ float pjt[6], wlp6[6], bin6[6];
    __shared__ float wprod[8];
    __shared__ float bp_s, bg_s;
    int tid=threadIdx.x;
    float C4=lgammaf(0.8f)-4.0f*lgammaf(0.2f);
    float C3=lgammaf(0.6f)-3.0f*lgammaf(0.2f);

    float part=0.0f;
    if(tid<60){
        const float* l=pwm_logits+tid*4;
        float m=fmaxf(fmaxf(l[0],l[1]),fmaxf(l[2],l[3]));
        float se=expf(l[0]-m)+expf(l[1]-m)+expf(l[2]-m)+expf(l[3]-m);
        float ls=logf(se);
        float dsum=0.0f;
        for(int c=0;c<4;c++) dsum+=l[c]-m-ls;
        part=fminf(3.0f, -0.8f*dsum+C4);
    }
    sa[tid]=part;
    if(tid<16) h1[tid]=mishf(wn_W1[tid]+wn_b1[tid]);
    __syncthreads();
    for(int s=128;s>0;s>>=1){ if(tid<s) sa[tid]+=sa[tid+s]; __syncthreads(); }
    float dirsum = sa[0];          // uniform read after final sync
    if(tid<16){
        float a=wn_b2[tid];
        for(int i=0;i<16;i++) a+=h1[i]*wn_W2[i*16+tid];
        h2[tid]=mishf(a);
    }
    __syncthreads();
    if(tid<6){
        int j=tid>>1;
        float a=wn_b3[j];
        for(int i=0;i<16;i++) a+=h2[i]*wn_W3[i*3+j];
        float mean=sigm(a)*15.0f+5.0f;
        float wv=(tid&1)?ceilf(mean):floorf(mean);
        float up=(wv>=20.0f)?1.0f:sigm((wv+0.5f-mean)*20.0f);
        float lo=(wv<=5.0f)?0.0f:sigm((wv-0.5f-mean)*20.0f);
        wlp6[tid]=logf(up-lo+1e-12f);
        pjt[tid]=expf(wlp6[tid]);
        bin6[tid]=lgammaf(16.0f)-lgammaf(wv+1.0f)-lgammaf(16.0f-wv)-15.0f*LN2F;
    }
    __syncthreads();
    if(tid==0){
        float bp=dirsum, bg=0.0f;
        for(int i=0;i<8;i++){
            int b0=(i>>2)&1, b1=(i>>1)&1, b2=i&1;
            float wp=pjt[b0]*pjt[2+b1]*pjt[4+b2];
            wprod[i]=wp;
            bp+=wp*(bin6[b0]+bin6[2+b1]+bin6[4+b2]);
            bg+=wp*(wlp6[b0]+wlp6[2+b1]+wlp6[4+b2]);
        }
        bp_s=bp; bg_s=bg;
    }
    __syncthreads();

    float pp=0.0f, pg=0.0f, px=0.0f;
    for(int idx=tid; idx<400; idx+=256){       // gamma Dirichlet prior
        int iw=idx/50, b=idx%50;
        const float* g=&ws[WS_GAMMA+(iw*50+b)*3];
        float lp=-0.8f*(logf(g[0])+logf(g[1])+logf(g[2]))+C3;
        pp += wprod[iw]*fminf(3.0f,lp);
    }
    for(int idx=tid; idx<300; idx+=256){       // z-branch contraction
        int It=idx/50, b=idx%50;
        int I=It>>1, t=It&1;
        float gs=0.0f;
        for(int iw=0;iw<8;iw++)
            if(((iw>>(2-I))&1)==t) gs+=ws[WS_GAMMA+(iw*50+b)*3+I];
        float G=pjt[It]*gs;
        pp += G*ws[WS_ZT+idx];
        pg += G*ws[WS_ZT+300+idx];
        px += G*ws[WS_ZT+600+idx];
    }
    sa[tid]=pp; sb[tid]=pg; sc[tid]=px;
    __syncthreads();
    for(int s=128;s>0;s>>=1){
        if(tid<s){ sa[tid]+=sa[tid+s]; sb[tid]+=sb[tid+s]; sc[tid]+=sc[tid+s]; }
        __syncthreads();
    }
    if(tid==0){
        float log_prior=bp_s+sa[0];
        float log_guide=bg_s+sb[0];
        out[0] = -sc[0] - log_prior + log_guide;
    }
}

extern "C" void kernel_launch(void* const* d_in, const int* in_sizes, int n_in,
                              void* d_out, int out_size, void* d_ws, size_t ws_size,
                              hipStream_t stream)
{
    const float* pwm_logits=(const float*)d_in[0];
    const float* wn_W1 =(const float*)d_in[1];
    const float* wn_b1 =(const float*)d_in[2];
    const float* wn_W2 =(const float*)d_in[3];
    const float* wn_b2 =(const float*)d_in[4];
    const float* wn_W3 =(const float*)d_in[5];
    const float* wn_b3 =(const float*)d_in[6];
    const float* gn_c1W=(const float*)d_in[7];
    const float* gn_c1b=(const float*)d_in[8];
    const float* gn_c2W=(const float*)d_in[9];
    const float* gn_c2b=(const float*)d_in[10];
    const float* gn_l1W=(const float*)d_in[11];
    const float* gn_l1b=(const float*)d_in[12];
    const float* gn_l2W=(const float*)d_in[13];
    const float* gn_l2b=(const float*)d_in[14];
    const float* zn_c1W=(const float*)d_in[15];
    const float* zn_c1b=(const float*)d_in[16];
    const float* zn_c2W=(const float*)d_in[17];
    const float* zn_c2b=(const float*)d_in[18];
    const float* zn_clsW=(const float*)d_in[19];
    const float* zn_clsb=(const float*)d_in[20];
    const float* zn_delW=(const float*)d_in[21];
    const float* zn_delb=(const float*)d_in[22];
    const int*   X     =(const int*)d_in[23];
    float* ws =(float*)d_ws;
    float* out=(float*)d_out;

    hipLaunchKernelGGL(kMain, dim3(700), dim3(256), 0, stream,
                       pwm_logits, wn_W1, wn_b1, wn_W2, wn_b2, wn_W3, wn_b3,
                       gn_c1W, gn_c1b, gn_c2W, gn_c2b, gn_l1W, gn_l1b, gn_l2W, gn_l2b,
                       zn_c1W, zn_c1b, zn_c2W, zn_c2b, zn_clsW, zn_clsb, zn_delW, zn_delb,
                       X, ws);
    hipLaunchKernelGGL(kFin, dim3(1),   dim3(256), 0, stream,
                       pwm_logits, wn_W1, wn_b1, wn_W2, wn_b2, wn_W3, wn_b3, ws, out);
}